// Round 3
// baseline (256.187 us; speedup 1.0000x reference)
//
#include <hip/hip_runtime.h>

#define PI_F 3.14159f

// ---------------------------------------------------------------------------
// Kernel A: per-batch MLP head -> per-channel PRE-SCALED affine params.
// 8 batches per block, 256 threads. Phase 1 keeps para in registers and
// broadcasts with v_readlane (no LDS); kk-loop unrolled x4 so 4 W1 loads are
// in flight (was 1 -> serial L2 latency). 8 batches/block halves W1 L2
// traffic (each block streams all 256 KB of W1). Accumulation order per
// batch is unchanged -> bitwise-identical results.
// params layout: [B][20][8] = (P0..P5, 0, 0):
// ix = P0*X + P1*Y + P2 ; iy = P3*X + P4*Y + P5, with grid_sample *9+8.5
// scaling and the +1 pad shift folded in.
// ---------------------------------------------------------------------------
__global__ __launch_bounds__(256) void params_kernel(
    const float* __restrict__ pc, const float* __restrict__ W1, const float* __restrict__ b1,
    const float* __restrict__ Ws, const float* __restrict__ bs,
    const float* __restrict__ Wr, const float* __restrict__ br,
    const float* __restrict__ Wt, const float* __restrict__ bt,
    float* __restrict__ params)
{
    __shared__ float hbuf[8][260];
    __shared__ float raw[8][80];

    const int t    = threadIdx.x;
    const int lane = t & 63;
    const int b0   = blockIdx.x * 8;

    float pval[8][4];
    #pragma unroll
    for (int g = 0; g < 8; ++g)
        #pragma unroll
        for (int c = 0; c < 4; ++c)
            pval[g][c] = pc[(size_t)(b0 + g) * 256 + c * 64 + lane];

    float acc[8];
    #pragma unroll
    for (int g = 0; g < 8; ++g) acc[g] = b1[t];

    #pragma unroll
    for (int c = 0; c < 4; ++c) {
        #pragma unroll 4
        for (int kk = 0; kk < 64; ++kk) {
            float w = W1[(c * 64 + kk) * 256 + t];
            #pragma unroll
            for (int g = 0; g < 8; ++g) {
                float pk = __int_as_float(
                    __builtin_amdgcn_readlane(__float_as_int(pval[g][c]), kk));
                acc[g] = fmaf(pk, w, acc[g]);
            }
        }
    }
    #pragma unroll
    for (int g = 0; g < 8; ++g) hbuf[g][t] = fmaxf(acc[g], 0.0f);
    __syncthreads();

    for (int task = t; task < 640; task += 256) {
        int g   = task / 80;
        int col = task - g * 80;
        const float* Wcol;
        float bias;
        int stride;
        if (col < 20)      { Wcol = Ws + col;        bias = bs[col];      stride = 20; }
        else if (col < 40) { Wcol = Wr + (col - 20); bias = br[col - 20]; stride = 20; }
        else               { Wcol = Wt + (col - 40); bias = bt[col - 40]; stride = 40; }
        const float4* h4 = (const float4*)hbuf[g];
        float a = bias;
        #pragma unroll 2
        for (int k4 = 0; k4 < 64; ++k4) {
            float4 h = h4[k4];
            int k = k4 * 4;
            a = fmaf(h.x, Wcol[k * stride], a);
            a = fmaf(h.y, Wcol[(k + 1) * stride], a);
            a = fmaf(h.z, Wcol[(k + 2) * stride], a);
            a = fmaf(h.w, Wcol[(k + 3) * stride], a);
        }
        raw[g][col] = a;
    }
    __syncthreads();

    for (int task = t; task < 160; task += 256) {
        int g = task / 20;
        int f = task - g * 20;
        float sc  = 2.0f / (1.0f + expf(-raw[g][f]));
        float ang = PI_F * tanhf(raw[g][20 + f]);
        float tx  = tanhf(raw[g][40 + 2 * f]);
        float ty  = tanhf(raw[g][40 + 2 * f + 1]);
        float c = cosf(ang), s = sinf(ang);
        float* o = params + ((size_t)(b0 + g) * 20 + f) * 8;
        o[0] = 9.0f * sc * c;  o[1] = -9.0f * sc * s;  o[2] = fmaf(9.0f, tx, 9.5f);
        o[3] = 9.0f * sc * s;  o[4] =  9.0f * sc * c;  o[5] = fmaf(9.0f, ty, 9.5f);
        o[6] = 0.0f;           o[7] = 0.0f;
    }
}

// ---------------------------------------------------------------------------
// Kernel B v4: ONE WAVE owns ONE (batch, channel); zero __syncthreads().
// Changes vs v3:
//  * image stride 21 (coprime with 32 banks) -> rotated gathers stop
//    aliasing LDS banks; taps at offsets {0,1,21,22}.
//  * point-PAIRING: 3 rounds of 162 pair-tasks (adjacent x) instead of
//    6 rounds of 324 points. y-div, Y and the store are shared per pair;
//    stage loads are dwordx2, output stores are dwordx2. Per-element
//    arithmetic is formula-identical to v3 (bitwise-same results).
// LDS = 4*448*4 = 7168 B; occupancy wave-limited at 8 blocks/CU (32/32).
// Zero-padding via coordinate clamp; border + row-20/col-20 overread
// cells zeroed so weight-0 taps stay finite.
// ---------------------------------------------------------------------------
__global__ __launch_bounds__(256, 8) void sample_kernel(
    const float* __restrict__ fmap, const float* __restrict__ params,
    float* __restrict__ out)
{
    __shared__ __align__(16) float lds[4][448];

    const int t    = threadIdx.x;
    const int lane = t & 63;
    const int w    = t >> 6;
    const int bid  = blockIdx.x;
    const int b    = bid / 5;
    const int c    = (bid - b * 5) * 4 + w;     // channel 0..19
    float* wv = lds[w];

    // --- affine params for this channel (issue early; wave-uniform addr)
    const float* pp = params + ((size_t)b * 20 + c) * 8;
    const float4 pA = *(const float4*)pp;
    const float2 pB = *(const float2*)(pp + 4);

    // --- zero the 124 pad cells in 2 rounds:
    //  round 0 (i=0..63):  i<21 -> row 0 (idx i) ; else idx 378+i (399..441)
    //  round 1 (i=64..123): i<70 -> idx 378+i (442..447);
    //                       else q=i-70: y=1+q/3, x in {0,19,20} by q%3
    {
        int i = lane;
        int idx = (i < 21) ? i : 378 + i;
        wv[idx] = 0.0f;
        i = 64 + lane;
        if (i < 124) {
            int idx2;
            if (i < 70) idx2 = 378 + i;
            else {
                int q = i - 70;
                int y = 1 + q / 3;
                int r = q - (q / 3) * 3;
                int x = (r == 0) ? 0 : 18 + r;     // 0, 19, 20
                idx2 = y * 21 + x;
            }
            wv[idx2] = 0.0f;
        }
    }

    // --- z-blend weights for this channel (iz = (40c-19)/38)
    const float izf = (40.0f * (float)c - 19.0f) * (1.0f / 38.0f);
    const float fz0 = floorf(izf);
    const int   z0  = (int)fz0;
    const float wzB = izf - fz0;
    const bool  v0  = (z0 >= 0);
    const bool  v1  = (z0 + 1 <= 19);
    const float ew0 = v0 ? (1.0f - wzB) : 0.0f;
    const float ew1 = v1 ? wzB : 0.0f;
    const float* fb = fmap + (size_t)b * 6480;
    const float* s0 = fb + (v0 ? z0 : 0) * 324;
    const float* s1 = fb + (v1 ? z0 + 1 : 19) * 324;

    // --- stage: blend 2 slices -> padded interior, 2 elems/lane/round
    #pragma unroll
    for (int it = 0; it < 3; ++it) {
        int k = it * 64 + lane;                  // pair index
        if (k < 162) {
            int i = 2 * k;
            float2 a  = *(const float2*)(s0 + i);   // 8B coalesced
            float2 bb = *(const float2*)(s1 + i);
            int y = k / 9;                       // i/18
            int x = 2 * (k - y * 9);
            int base = (y + 1) * 21 + (x + 1);
            wv[base]     = fmaf(a.x, ew0, bb.x * ew1);
            wv[base + 1] = fmaf(a.y, ew0, bb.y * ew1);
        }
    }

    // --- sample 324 points as 162 adjacent-x pairs, dwordx2 stores
    float* ob = out + (size_t)b * 6480 + c * 324;
    #pragma unroll
    for (int it = 0; it < 3; ++it) {
        int k = it * 64 + lane;
        if (k < 162) {
            int y  = k / 9;
            int x0 = 2 * (k - y * 9);
            float Y = (float)y * (2.0f / 17.0f) - 1.0f;
            float r2[2];
            #pragma unroll
            for (int q = 0; q < 2; ++q) {
                float X = (float)(x0 + q) * (2.0f / 17.0f) - 1.0f;
                float ix = fmaf(pA.x, X, fmaf(pA.y, Y, pA.z));
                float iy = fmaf(pA.w, X, fmaf(pB.x, Y, pB.y));
                ix = fminf(fmaxf(ix, 0.0f), 19.0f);
                iy = fminf(fmaxf(iy, 0.0f), 19.0f);
                float fx = floorf(ix), fy = floorf(iy);
                float u1 = ix - fx, vv = iy - fy;
                const float* s = wv + ((int)fy * 21 + (int)fx);
                float t00 = s[0], t01 = s[1], t10 = s[21], t11 = s[22];
                float u0 = 1.0f - u1, vc = 1.0f - vv;
                r2[q] = fmaf(fmaf(t01, u1, t00 * u0), vc,
                             fmaf(t11, u1, t10 * u0) * vv);
            }
            *(float2*)(ob + y * 18 + x0) = make_float2(r2[0], r2[1]);
        }
    }
}

extern "C" void kernel_launch(void* const* d_in, const int* in_sizes, int n_in,
                              void* d_out, int out_size, void* d_ws, size_t ws_size,
                              hipStream_t stream)
{
    const float* fmap = (const float*)d_in[0];
    const float* pc   = (const float*)d_in[1];
    const float* W1   = (const float*)d_in[2];
    const float* b1   = (const float*)d_in[3];
    const float* Ws   = (const float*)d_in[4];
    const float* bs   = (const float*)d_in[5];
    const float* Wr   = (const float*)d_in[6];
    const float* br   = (const float*)d_in[7];
    const float* Wt   = (const float*)d_in[8];
    const float* bt   = (const float*)d_in[9];
    float* out    = (float*)d_out;
    float* params = (float*)d_ws;     // B*20*8 floats

    const int B = in_sizes[0] / (20 * 18 * 18);   // 4096

    params_kernel<<<B / 8, 256, 0, stream>>>(pc, W1, b1, Ws, bs, Wr, br, Wt, bt, params);
    sample_kernel<<<B * 5, 256, 0, stream>>>(fmap, params, out);
}

// Round 4
// 243.281 us; speedup vs baseline: 1.0531x; 1.0531x over previous
//
#include <hip/hip_runtime.h>

#define PI_F 3.14159f

// ---------------------------------------------------------------------------
// Kernel A v3: per-batch MLP head -> per-channel PRE-SCALED affine params.
// 4 batches per block, 256 threads, 1024 blocks (4 blocks/CU, 16 waves/CU).
// Phase 1: thread t owns h[g][t] for 4 batches. pc is indexed with a
// BLOCK-UNIFORM address -> compiler emits s_load (merged dwordx4+) and the
// inner FMA is v_fmac_f32 v,s,v: no v_readlane at all (round-2 version spent
// half its phase-1 instructions on readlane broadcasts). kk ascends 0..255
// exactly as before -> bitwise-identical accumulation.
// params layout: [B][20][8] = (P0..P5, 0, 0):
// ix = P0*X + P1*Y + P2 ; iy = P3*X + P4*Y + P5, with grid_sample *9+8.5
// scaling and the +1 pad shift folded in.
// ---------------------------------------------------------------------------
__global__ __launch_bounds__(256) void params_kernel(
    const float* __restrict__ pc, const float* __restrict__ W1, const float* __restrict__ b1,
    const float* __restrict__ Ws, const float* __restrict__ bs,
    const float* __restrict__ Wr, const float* __restrict__ br,
    const float* __restrict__ Wt, const float* __restrict__ bt,
    float* __restrict__ params)
{
    __shared__ float hbuf[4][260];
    __shared__ float raw[4][80];

    const int t  = threadIdx.x;
    const int b0 = blockIdx.x * 4;

    float acc[4];
    #pragma unroll
    for (int g = 0; g < 4; ++g) acc[g] = b1[t];

    const float* pcb = pc + (size_t)b0 * 256;   // block-uniform base

    #pragma unroll 16
    for (int kk = 0; kk < 256; ++kk) {
        float w = W1[(size_t)kk * 256 + t];     // coalesced vector load (L2-hot)
        #pragma unroll
        for (int g = 0; g < 4; ++g)
            acc[g] = fmaf(pcb[g * 256 + kk], w, acc[g]);  // uniform -> s_load
    }
    #pragma unroll
    for (int g = 0; g < 4; ++g) hbuf[g][t] = fmaxf(acc[g], 0.0f);
    __syncthreads();

    for (int task = t; task < 320; task += 256) {
        int g   = task / 80;
        int col = task - g * 80;
        const float* Wcol;
        float bias;
        int stride;
        if (col < 20)      { Wcol = Ws + col;        bias = bs[col];      stride = 20; }
        else if (col < 40) { Wcol = Wr + (col - 20); bias = br[col - 20]; stride = 20; }
        else               { Wcol = Wt + (col - 40); bias = bt[col - 40]; stride = 40; }
        const float4* h4 = (const float4*)hbuf[g];
        float a = bias;
        #pragma unroll 2
        for (int k4 = 0; k4 < 64; ++k4) {
            float4 h = h4[k4];
            int k = k4 * 4;
            a = fmaf(h.x, Wcol[k * stride], a);
            a = fmaf(h.y, Wcol[(k + 1) * stride], a);
            a = fmaf(h.z, Wcol[(k + 2) * stride], a);
            a = fmaf(h.w, Wcol[(k + 3) * stride], a);
        }
        raw[g][col] = a;
    }
    __syncthreads();

    for (int task = t; task < 80; task += 256) {
        int g = task / 20;
        int f = task - g * 20;
        float sc  = 2.0f / (1.0f + expf(-raw[g][f]));
        float ang = PI_F * tanhf(raw[g][20 + f]);
        float tx  = tanhf(raw[g][40 + 2 * f]);
        float ty  = tanhf(raw[g][40 + 2 * f + 1]);
        float c = cosf(ang), s = sinf(ang);
        float* o = params + ((size_t)(b0 + g) * 20 + f) * 8;
        o[0] = 9.0f * sc * c;  o[1] = -9.0f * sc * s;  o[2] = fmaf(9.0f, tx, 9.5f);
        o[3] = 9.0f * sc * s;  o[4] =  9.0f * sc * c;  o[5] = fmaf(9.0f, ty, 9.5f);
        o[6] = 0.0f;           o[7] = 0.0f;
    }
}

// ---------------------------------------------------------------------------
// Kernel B v4 (unchanged from round 3 — the control): ONE WAVE owns ONE
// (batch, channel); zero __syncthreads(). Stride-21 LDS image (coprime with
// 32 banks), taps {0,1,21,22}; 162 adjacent-x pair-tasks per phase with
// dwordx2 loads/stores. LDS = 4*448*4 = 7168 B; 8 blocks/CU (32/32 waves).
// Zero-padding via coordinate clamp; border + overread cells zeroed.
// ---------------------------------------------------------------------------
__global__ __launch_bounds__(256, 8) void sample_kernel(
    const float* __restrict__ fmap, const float* __restrict__ params,
    float* __restrict__ out)
{
    __shared__ __align__(16) float lds[4][448];

    const int t    = threadIdx.x;
    const int lane = t & 63;
    const int w    = t >> 6;
    const int bid  = blockIdx.x;
    const int b    = bid / 5;
    const int c    = (bid - b * 5) * 4 + w;     // channel 0..19
    float* wv = lds[w];

    // --- affine params for this channel (issue early; wave-uniform addr)
    const float* pp = params + ((size_t)b * 20 + c) * 8;
    const float4 pA = *(const float4*)pp;
    const float2 pB = *(const float2*)(pp + 4);

    // --- zero the 124 pad cells in 2 rounds
    {
        int i = lane;
        int idx = (i < 21) ? i : 378 + i;
        wv[idx] = 0.0f;
        i = 64 + lane;
        if (i < 124) {
            int idx2;
            if (i < 70) idx2 = 378 + i;
            else {
                int q = i - 70;
                int y = 1 + q / 3;
                int r = q - (q / 3) * 3;
                int x = (r == 0) ? 0 : 18 + r;     // 0, 19, 20
                idx2 = y * 21 + x;
            }
            wv[idx2] = 0.0f;
        }
    }

    // --- z-blend weights for this channel (iz = (40c-19)/38)
    const float izf = (40.0f * (float)c - 19.0f) * (1.0f / 38.0f);
    const float fz0 = floorf(izf);
    const int   z0  = (int)fz0;
    const float wzB = izf - fz0;
    const bool  v0  = (z0 >= 0);
    const bool  v1  = (z0 + 1 <= 19);
    const float ew0 = v0 ? (1.0f - wzB) : 0.0f;
    const float ew1 = v1 ? wzB : 0.0f;
    const float* fb = fmap + (size_t)b * 6480;
    const float* s0 = fb + (v0 ? z0 : 0) * 324;
    const float* s1 = fb + (v1 ? z0 + 1 : 19) * 324;

    // --- stage: blend 2 slices -> padded interior, 2 elems/lane/round
    #pragma unroll
    for (int it = 0; it < 3; ++it) {
        int k = it * 64 + lane;                  // pair index
        if (k < 162) {
            int i = 2 * k;
            float2 a  = *(const float2*)(s0 + i);   // 8B coalesced
            float2 bb = *(const float2*)(s1 + i);
            int y = k / 9;                       // i/18
            int x = 2 * (k - y * 9);
            int base = (y + 1) * 21 + (x + 1);
            wv[base]     = fmaf(a.x, ew0, bb.x * ew1);
            wv[base + 1] = fmaf(a.y, ew0, bb.y * ew1);
        }
    }

    // --- sample 324 points as 162 adjacent-x pairs, dwordx2 stores
    float* ob = out + (size_t)b * 6480 + c * 324;
    #pragma unroll
    for (int it = 0; it < 3; ++it) {
        int k = it * 64 + lane;
        if (k < 162) {
            int y  = k / 9;
            int x0 = 2 * (k - y * 9);
            float Y = (float)y * (2.0f / 17.0f) - 1.0f;
            float r2[2];
            #pragma unroll
            for (int q = 0; q < 2; ++q) {
                float X = (float)(x0 + q) * (2.0f / 17.0f) - 1.0f;
                float ix = fmaf(pA.x, X, fmaf(pA.y, Y, pA.z));
                float iy = fmaf(pA.w, X, fmaf(pB.x, Y, pB.y));
                ix = fminf(fmaxf(ix, 0.0f), 19.0f);
                iy = fminf(fmaxf(iy, 0.0f), 19.0f);
                float fx = floorf(ix), fy = floorf(iy);
                float u1 = ix - fx, vv = iy - fy;
                const float* s = wv + ((int)fy * 21 + (int)fx);
                float t00 = s[0], t01 = s[1], t10 = s[21], t11 = s[22];
                float u0 = 1.0f - u1, vc = 1.0f - vv;
                r2[q] = fmaf(fmaf(t01, u1, t00 * u0), vc,
                             fmaf(t11, u1, t10 * u0) * vv);
            }
            *(float2*)(ob + y * 18 + x0) = make_float2(r2[0], r2[1]);
        }
    }
}

extern "C" void kernel_launch(void* const* d_in, const int* in_sizes, int n_in,
                              void* d_out, int out_size, void* d_ws, size_t ws_size,
                              hipStream_t stream)
{
    const float* fmap = (const float*)d_in[0];
    const float* pc   = (const float*)d_in[1];
    const float* W1   = (const float*)d_in[2];
    const float* b1   = (const float*)d_in[3];
    const float* Ws   = (const float*)d_in[4];
    const float* bs   = (const float*)d_in[5];
    const float* Wr   = (const float*)d_in[6];
    const float* br   = (const float*)d_in[7];
    const float* Wt   = (const float*)d_in[8];
    const float* bt   = (const float*)d_in[9];
    float* out    = (float*)d_out;
    float* params = (float*)d_ws;     // B*20*8 floats

    const int B = in_sizes[0] / (20 * 18 * 18);   // 4096

    params_kernel<<<B / 4, 256, 0, stream>>>(pc, W1, b1, Ws, bs, Wr, br, Wt, bt, params);
    sample_kernel<<<B * 5, 256, 0, stream>>>(fmap, params, out);
}

// Round 5
// 229.536 us; speedup vs baseline: 1.1161x; 1.0599x over previous
//
#include <hip/hip_runtime.h>

#define PI_F 3.14159f

// ---------------------------------------------------------------------------
// Kernel A v4: per-batch MLP head -> per-channel PRE-SCALED affine params.
// 4 batches per block, 256 threads, 1024 blocks (4 blocks/CU, 16 waves/CU).
// Phase 1: pc is staged into LDS (4 KB) and read back as ds_read_b128 at a
// WAVE-UNIFORM address -> hardware broadcast, no bank conflicts, no reliance
// on the compiler proving s_load-ability (round-4 evidence says it didn't:
// scalar-"uniform" global indexing performed identically to readlane).
// kk ascends 0..255 exactly as before -> bitwise-identical accumulation.
// params layout: [B][20][8] = (P0..P5, 0, 0):
// ix = P0*X + P1*Y + P2 ; iy = P3*X + P4*Y + P5, with grid_sample *9+8.5
// scaling and the +1 pad shift folded in.
// ---------------------------------------------------------------------------
__global__ __launch_bounds__(256) void params_kernel(
    const float* __restrict__ pc, const float* __restrict__ W1, const float* __restrict__ b1,
    const float* __restrict__ Ws, const float* __restrict__ bs,
    const float* __restrict__ Wr, const float* __restrict__ br,
    const float* __restrict__ Wt, const float* __restrict__ bt,
    float* __restrict__ params)
{
    __shared__ float hbuf[4][260];
    __shared__ float raw[4][80];
    __shared__ __align__(16) float pcs[4][256];

    const int t  = threadIdx.x;
    const int b0 = blockIdx.x * 4;

    #pragma unroll
    for (int g = 0; g < 4; ++g)
        pcs[g][t] = pc[(size_t)(b0 + g) * 256 + t];   // coalesced, 1 dword/thread

    float acc[4];
    #pragma unroll
    for (int g = 0; g < 4; ++g) acc[g] = b1[t];
    __syncthreads();

    const float4* p40 = (const float4*)pcs[0];
    const float4* p41 = (const float4*)pcs[1];
    const float4* p42 = (const float4*)pcs[2];
    const float4* p43 = (const float4*)pcs[3];

    #pragma unroll 4
    for (int k4 = 0; k4 < 64; ++k4) {
        const float* wp = W1 + (size_t)k4 * 1024 + t;   // 4 coalesced rows
        float w0 = wp[0], w1 = wp[256], w2 = wp[512], w3 = wp[768];
        float4 p0 = p40[k4];                 // ds_read_b128, broadcast
        float4 p1 = p41[k4];
        float4 p2 = p42[k4];
        float4 p3 = p43[k4];
        // kk = 4*k4 + 0
        acc[0] = fmaf(p0.x, w0, acc[0]);
        acc[1] = fmaf(p1.x, w0, acc[1]);
        acc[2] = fmaf(p2.x, w0, acc[2]);
        acc[3] = fmaf(p3.x, w0, acc[3]);
        // kk = 4*k4 + 1
        acc[0] = fmaf(p0.y, w1, acc[0]);
        acc[1] = fmaf(p1.y, w1, acc[1]);
        acc[2] = fmaf(p2.y, w1, acc[2]);
        acc[3] = fmaf(p3.y, w1, acc[3]);
        // kk = 4*k4 + 2
        acc[0] = fmaf(p0.z, w2, acc[0]);
        acc[1] = fmaf(p1.z, w2, acc[1]);
        acc[2] = fmaf(p2.z, w2, acc[2]);
        acc[3] = fmaf(p3.z, w2, acc[3]);
        // kk = 4*k4 + 3
        acc[0] = fmaf(p0.w, w3, acc[0]);
        acc[1] = fmaf(p1.w, w3, acc[1]);
        acc[2] = fmaf(p2.w, w3, acc[2]);
        acc[3] = fmaf(p3.w, w3, acc[3]);
    }
    #pragma unroll
    for (int g = 0; g < 4; ++g) hbuf[g][t] = fmaxf(acc[g], 0.0f);
    __syncthreads();

    for (int task = t; task < 320; task += 256) {
        int g   = task / 80;
        int col = task - g * 80;
        const float* Wcol;
        float bias;
        int stride;
        if (col < 20)      { Wcol = Ws + col;        bias = bs[col];      stride = 20; }
        else if (col < 40) { Wcol = Wr + (col - 20); bias = br[col - 20]; stride = 20; }
        else               { Wcol = Wt + (col - 40); bias = bt[col - 40]; stride = 40; }
        const float4* h4 = (const float4*)hbuf[g];
        float a = bias;
        #pragma unroll 4
        for (int k4 = 0; k4 < 64; ++k4) {
            float4 h = h4[k4];
            int k = k4 * 4;
            a = fmaf(h.x, Wcol[k * stride], a);
            a = fmaf(h.y, Wcol[(k + 1) * stride], a);
            a = fmaf(h.z, Wcol[(k + 2) * stride], a);
            a = fmaf(h.w, Wcol[(k + 3) * stride], a);
        }
        raw[g][col] = a;
    }
    __syncthreads();

    for (int task = t; task < 80; task += 256) {
        int g = task / 20;
        int f = task - g * 20;
        float sc  = 2.0f / (1.0f + expf(-raw[g][f]));
        float ang = PI_F * tanhf(raw[g][20 + f]);
        float tx  = tanhf(raw[g][40 + 2 * f]);
        float ty  = tanhf(raw[g][40 + 2 * f + 1]);
        float c = cosf(ang), s = sinf(ang);
        float* o = params + ((size_t)(b0 + g) * 20 + f) * 8;
        o[0] = 9.0f * sc * c;  o[1] = -9.0f * sc * s;  o[2] = fmaf(9.0f, tx, 9.5f);
        o[3] = 9.0f * sc * s;  o[4] =  9.0f * sc * c;  o[5] = fmaf(9.0f, ty, 9.5f);
        o[6] = 0.0f;           o[7] = 0.0f;
    }
}

// ---------------------------------------------------------------------------
// Kernel B v5: ONE WAVE owns ONE (batch, channel); zero __syncthreads().
// v4 + load-first reorder: the 6 global slice loads (dwordx2, clamped index
// so no exec mask delays issue) are issued BEFORE the pad-zeroing, hiding
// ~900-cycle HBM latency under ~60 setup/zeroing instructions. Stride-21
// LDS image (coprime with 32 banks), taps {0,1,21,22}; 162 adjacent-x
// pair-tasks with dwordx2 stores. LDS = 4*448*4 = 7168 B; 8 blocks/CU.
// ---------------------------------------------------------------------------
__global__ __launch_bounds__(256, 8) void sample_kernel(
    const float* __restrict__ fmap, const float* __restrict__ params,
    float* __restrict__ out)
{
    __shared__ __align__(16) float lds[4][448];

    const int t    = threadIdx.x;
    const int lane = t & 63;
    const int w    = t >> 6;
    const int bid  = blockIdx.x;
    const int b    = bid / 5;
    const int c    = (bid - b * 5) * 4 + w;     // channel 0..19
    float* wv = lds[w];

    // --- affine params for this channel (issue early; wave-uniform addr)
    const float* pp = params + ((size_t)b * 20 + c) * 8;
    const float4 pA = *(const float4*)pp;
    const float2 pB = *(const float2*)(pp + 4);

    // --- z-blend setup (iz = (40c-19)/38)
    const float izf = (40.0f * (float)c - 19.0f) * (1.0f / 38.0f);
    const float fz0 = floorf(izf);
    const int   z0  = (int)fz0;
    const float wzB = izf - fz0;
    const bool  v0  = (z0 >= 0);
    const bool  v1  = (z0 + 1 <= 19);
    const float ew0 = v0 ? (1.0f - wzB) : 0.0f;
    const float ew1 = v1 ? wzB : 0.0f;
    const float* fb = fmap + (size_t)b * 6480;
    const float* s0 = fb + (v0 ? z0 : 0) * 324;
    const float* s1 = fb + (v1 ? z0 + 1 : 19) * 324;

    // --- 1) ISSUE the 6 slice loads first (clamped index: unconditional,
    //        in-bounds, masked lanes load k=161's data and discard)
    float2 a2[3], b2[3];
    #pragma unroll
    for (int it = 0; it < 3; ++it) {
        int k  = it * 64 + lane;
        int kc = (k < 162) ? k : 161;
        a2[it] = *(const float2*)(s0 + 2 * kc);
        b2[it] = *(const float2*)(s1 + 2 * kc);
    }

    // --- 2) zero the 124 pad cells (latency of (1) hides under this)
    {
        int i = lane;
        int idx = (i < 21) ? i : 378 + i;
        wv[idx] = 0.0f;
        i = 64 + lane;
        if (i < 124) {
            int idx2;
            if (i < 70) idx2 = 378 + i;
            else {
                int q = i - 70;
                int y = 1 + q / 3;
                int r = q - (q / 3) * 3;
                int x = (r == 0) ? 0 : 18 + r;     // 0, 19, 20
                idx2 = y * 21 + x;
            }
            wv[idx2] = 0.0f;
        }
    }

    // --- 3) blend -> padded interior, 2 elems/lane/round
    #pragma unroll
    for (int it = 0; it < 3; ++it) {
        int k = it * 64 + lane;                  // pair index
        if (k < 162) {
            int y = k / 9;
            int x = 2 * (k - y * 9);
            int base = (y + 1) * 21 + (x + 1);
            wv[base]     = fmaf(a2[it].x, ew0, b2[it].x * ew1);
            wv[base + 1] = fmaf(a2[it].y, ew0, b2[it].y * ew1);
        }
    }

    // --- 4) sample 324 points as 162 adjacent-x pairs, dwordx2 stores
    float* ob = out + (size_t)b * 6480 + c * 324;
    #pragma unroll
    for (int it = 0; it < 3; ++it) {
        int k = it * 64 + lane;
        if (k < 162) {
            int y  = k / 9;
            int x0 = 2 * (k - y * 9);
            float Y = (float)y * (2.0f / 17.0f) - 1.0f;
            float r2[2];
            #pragma unroll
            for (int q = 0; q < 2; ++q) {
                float X = (float)(x0 + q) * (2.0f / 17.0f) - 1.0f;
                float ix = fmaf(pA.x, X, fmaf(pA.y, Y, pA.z));
                float iy = fmaf(pA.w, X, fmaf(pB.x, Y, pB.y));
                ix = fminf(fmaxf(ix, 0.0f), 19.0f);
                iy = fminf(fmaxf(iy, 0.0f), 19.0f);
                float fx = floorf(ix), fy = floorf(iy);
                float u1 = ix - fx, vv = iy - fy;
                const float* s = wv + ((int)fy * 21 + (int)fx);
                float t00 = s[0], t01 = s[1], t10 = s[21], t11 = s[22];
                float u0 = 1.0f - u1, vc = 1.0f - vv;
                r2[q] = fmaf(fmaf(t01, u1, t00 * u0), vc,
                             fmaf(t11, u1, t10 * u0) * vv);
            }
            *(float2*)(ob + y * 18 + x0) = make_float2(r2[0], r2[1]);
        }
    }
}

extern "C" void kernel_launch(void* const* d_in, const int* in_sizes, int n_in,
                              void* d_out, int out_size, void* d_ws, size_t ws_size,
                              hipStream_t stream)
{
    const float* fmap = (const float*)d_in[0];
    const float* pc   = (const float*)d_in[1];
    const float* W1   = (const float*)d_in[2];
    const float* b1   = (const float*)d_in[3];
    const float* Ws   = (const float*)d_in[4];
    const float* bs   = (const float*)d_in[5];
    const float* Wr   = (const float*)d_in[6];
    const float* br   = (const float*)d_in[7];
    const float* Wt   = (const float*)d_in[8];
    const float* bt   = (const float*)d_in[9];
    float* out    = (float*)d_out;
    float* params = (float*)d_ws;     // B*20*8 floats

    const int B = in_sizes[0] / (20 * 18 * 18);   // 4096

    params_kernel<<<B / 4, 256, 0, stream>>>(pc, W1, b1, Ws, bs, Wr, br, Wt, bt, params);
    sample_kernel<<<B * 5, 256, 0, stream>>>(fmap, params, out);
}